// Round 14
// baseline (100.827 us; speedup 1.0000x reference)
//
#include <hip/hip_runtime.h>

typedef _Float16 h8 __attribute__((ext_vector_type(8)));
typedef _Float16 h4 __attribute__((ext_vector_type(4)));
typedef _Float16 h2 __attribute__((ext_vector_type(2)));
typedef float f4 __attribute__((ext_vector_type(4)));
typedef float f16v __attribute__((ext_vector_type(16)));

#define HSTRIDE 104 // halves per comb row (208 B, 16B-aligned)

// ONE WAVE = ONE TREE, 32x32x16 MFMA, software-pipelined: ping-pong bf
// buffers hide each tile's LDS/VALU operand prep under the previous tile's
// MFMA burst. In-place comb ring: level tile i reads rows 32i..32i+31,
// writes 16i..16i+15; every prefetch below reads rows whose writes precede
// it in program order (same-wave DS pipe is in-order -> safe, barrier-free).
__global__ __launch_bounds__(64, 1)
void grnn_fused(const float* __restrict__ times,
                const float* __restrict__ Qw,
                const float* __restrict__ Qb,
                const float* __restrict__ Ww,
                const float* __restrict__ Wb,
                const float* __restrict__ Pw,
                const float* __restrict__ Pb,
                float* __restrict__ out)
{
  __shared__ __align__(16) _Float16 Cs[128][HSTRIDE]; // 26624 B comb buffer
  __shared__ __align__(16) _Float16 trash[512];       // dead-lane store sink
  __shared__ __align__(4)  _Float16 ts_fold[512];     // heap t[0..510] as f16
  __shared__ __align__(4)  h2 tsp[256];               // leaf pair (t[511+2n], t[512+2n])

  const int lane = threadIdx.x;        // 0..63
  const int c    = lane & 31;          // node/feature column
  const int hw   = lane >> 5;          // k half: k = 16kc + 8hw + j
  const int tree = blockIdx.x;

  // ---- stage times (single wave: no barriers ever) ----
  {
    const float* tg = times + tree * 1023;
    #pragma unroll
    for (int q = 0; q < 8; ++q) {
      const int ix = lane + 64 * q;
      if (ix < 511) ts_fold[ix] = (_Float16)tg[ix];
    }
    #pragma unroll
    for (int q = 0; q < 4; ++q) {
      const int pr = lane + 64 * q;
      tsp[pr] = (h2){(_Float16)tg[511 + 2 * pr], (_Float16)tg[512 + 2 * pr]};
    }
  }

  // ---- persistent W fragments as MFMA A operand: wf[ft][kc] holds
  //      A[f=32ft+c][k=16kc+8hw+j]; fold k=100 -> Qw[f], k=101 -> Qb+Wb ----
  h8 wf[4][7];
  #pragma unroll
  for (int ft = 0; ft < 4; ++ft) {
    const int r = 32 * ft + c;
    #pragma unroll
    for (int kc = 0; kc < 7; ++kc) {
      h8 v;
      #pragma unroll
      for (int j = 0; j < 8; ++j) v[j] = (_Float16)0.f;
      if (r < 100) {
        if (kc < 6) {
          const int kb = 16 * kc + 8 * hw;
          const f4 w0 = *(const f4*)&Ww[r * 100 + kb];
          const f4 w1 = *(const f4*)&Ww[r * 100 + kb + 4];
          #pragma unroll
          for (int j = 0; j < 4; ++j) {
            v[j]     = (_Float16)w0[j];
            v[j + 4] = (_Float16)w1[j];
          }
        } else if (hw == 0) {            // k = 96..103
          const f4 w0 = *(const f4*)&Ww[r * 100 + 96];
          #pragma unroll
          for (int j = 0; j < 4; ++j) v[j] = (_Float16)w0[j];
          v[4] = (_Float16)Qw[r];        // k=100
          v[5] = (_Float16)(Qb[r] + Wb[r]); // k=101
        }
      }
      wf[ft][kc] = v;
    }
  }

  // ---- leaf Q vectors in REGISTERS (live only through L8) ----
  h8 qwp[7], qbp[7];
  #pragma unroll
  for (int kc = 0; kc < 7; ++kc) {
    #pragma unroll
    for (int j = 0; j < 8; ++j) {
      const int ix = 16 * kc + 8 * hw + j;
      qwp[kc][j] = (ix < 100) ? (_Float16)Qw[ix] : (_Float16)0.f;
      qbp[kc][j] = (ix < 100) ? (_Float16)Qb[ix] : (_Float16)0.f;
    }
  }

// MFMA burst (4 independent ft chains x 7 kc) + epilogue: relu -> pack f16
// -> (non-root) DPP quad_perm(1,0,3,2) sibling add (lane^1 = node n^1) ->
// h4 store at col 32ft+8g+4hw. ft3 real only for hw==0,g==0 (feat 96..99).
#define DO_TILE(BF, BSE, DODPP) do {                                          \
    f16v acc_[4];                                                             \
    _Pragma("unroll")                                                         \
    for (int ft_ = 0; ft_ < 4; ++ft_)                                         \
      _Pragma("unroll")                                                       \
      for (int e_ = 0; e_ < 16; ++e_) acc_[ft_][e_] = 0.f;                    \
    _Pragma("unroll")                                                         \
    for (int kc_ = 0; kc_ < 7; ++kc_) {                                       \
      _Pragma("unroll")                                                       \
      for (int ft_ = 0; ft_ < 4; ++ft_)                                       \
        acc_[ft_] = __builtin_amdgcn_mfma_f32_32x32x16_f16(wf[ft_][kc_],      \
                                              BF[kc_], acc_[ft_], 0, 0, 0);   \
    }                                                                         \
    _Float16* b3_ = (hw == 0) ? (BSE) : &trash[lane * 4];                     \
    _Pragma("unroll")                                                         \
    for (int ft_ = 0; ft_ < 4; ++ft_) {                                       \
      _Pragma("unroll")                                                       \
      for (int g_ = 0; g_ < 4; ++g_) {                                        \
        if (ft_ < 3 || (g_ == 0)) {                                           \
          float a0_ = fmaxf(acc_[ft_][4 * g_ + 0], 0.f);                      \
          float a1_ = fmaxf(acc_[ft_][4 * g_ + 1], 0.f);                      \
          float a2_ = fmaxf(acc_[ft_][4 * g_ + 2], 0.f);                      \
          float a3_ = fmaxf(acc_[ft_][4 * g_ + 3], 0.f);                      \
          h2 lo_ = __builtin_bit_cast(h2,                                     \
                       __builtin_amdgcn_cvt_pkrtz(a0_, a1_));                 \
          h2 hi_ = __builtin_bit_cast(h2,                                     \
                       __builtin_amdgcn_cvt_pkrtz(a2_, a3_));                 \
          if (DODPP) {                                                        \
            int d0_ = __builtin_amdgcn_mov_dpp(__builtin_bit_cast(int, lo_),  \
                                               0xB1, 0xF, 0xF, true);         \
            int d1_ = __builtin_amdgcn_mov_dpp(__builtin_bit_cast(int, hi_),  \
                                               0xB1, 0xF, 0xF, true);         \
            lo_ = lo_ + __builtin_bit_cast(h2, d0_);                          \
            hi_ = hi_ + __builtin_bit_cast(h2, d1_);                          \
          }                                                                   \
          h4 hv_ = {lo_[0], lo_[1], hi_[0], hi_[1]};                          \
          *(h4*)(((ft_ == 3) ? b3_ : (BSE)) + 32 * ft_ + 8 * g_ + 4 * hw)     \
              = hv_;                                                          \
        }                                                                     \
      }                                                                       \
    }                                                                         \
  } while (0)

// B fragments: comb row RBASE + (c & RMASK); fold t at k=100, 1 at k=101.
#define LOAD_B(BF, RBASE, RMASK, TSIB) do {                                   \
    const int cm_ = c & (RMASK);                                              \
    const int row_ = (RBASE) + cm_;                                           \
    _Pragma("unroll")                                                         \
    for (int kc_ = 0; kc_ < 6; ++kc_)                                         \
      BF[kc_] = *(const h8*)&Cs[row_][16 * kc_ + 8 * hw];                     \
    if (hw == 0) {                                                            \
      h4 lo_ = *(const h4*)&Cs[row_][96];                                     \
      h4 hi_ = {ts_fold[(TSIB) + cm_], (_Float16)1.f,                         \
                (_Float16)0.f, (_Float16)0.f};                                \
      BF[6] = __builtin_shufflevector(lo_, hi_, 0, 1, 2, 3, 4, 5, 6, 7);      \
    } else {                                                                  \
      _Pragma("unroll")                                                       \
      for (int j_ = 0; j_ < 8; ++j_) BF[6][j_] = (_Float16)0.f;               \
    }                                                                         \
  } while (0)

// Leaf-tile B operand built in packed-f16 VALU (no Cs reads).
#define LEAF_BUILD(BF, I) do {                                                \
    const h2 tp_ = tsp[32 * (I) + c];                                         \
    const _Float16 t0_ = tp_[0], t1_ = tp_[1];                                \
    const h8 z8_ = {(_Float16)0.f, (_Float16)0.f, (_Float16)0.f,              \
                    (_Float16)0.f, (_Float16)0.f, (_Float16)0.f,              \
                    (_Float16)0.f, (_Float16)0.f};                            \
    _Pragma("unroll")                                                         \
    for (int kc_ = 0; kc_ < 7; ++kc_) {                                       \
      h8 a_ = __builtin_elementwise_max(qwp[kc_] * t0_ + qbp[kc_], z8_);      \
      h8 b_ = __builtin_elementwise_max(qwp[kc_] * t1_ + qbp[kc_], z8_);      \
      BF[kc_] = a_ + b_;                                                      \
    }                                                                         \
    if (hw == 0) {                                                            \
      BF[6][4] = ts_fold[255 + 32 * (I) + c];                                 \
      BF[6][5] = (_Float16)1.f;                                               \
    }                                                                         \
  } while (0)

// Store-base pointer: even c, c<NN -> comb row WROW+(c>>1); else trash.
#define BASE_PTR(WROW, NN)                                                    \
    ((((c & 1) == 0) && (c < (NN))) ? &Cs[(WROW) + (c >> 1)][0]               \
                                    : &trash[lane * 4])

  h8 bfA[7], bfB[7];

  // ---- level 8 (8 tiles): ping-pong — build(i+1) overlaps DO(i) ----
  LEAF_BUILD(bfA, 0);
  LEAF_BUILD(bfB, 1);  DO_TILE(bfA, BASE_PTR(0, 32), 1);
  LEAF_BUILD(bfA, 2);  DO_TILE(bfB, BASE_PTR(16, 32), 1);
  LEAF_BUILD(bfB, 3);  DO_TILE(bfA, BASE_PTR(32, 32), 1);
  LEAF_BUILD(bfA, 4);  DO_TILE(bfB, BASE_PTR(48, 32), 1);
  LEAF_BUILD(bfB, 5);  DO_TILE(bfA, BASE_PTR(64, 32), 1);
  LEAF_BUILD(bfA, 6);  DO_TILE(bfB, BASE_PTR(80, 32), 1);
  LEAF_BUILD(bfB, 7);  DO_TILE(bfA, BASE_PTR(96, 32), 1);
                       DO_TILE(bfB, BASE_PTR(112, 32), 1);

  // ---- levels 7..5: one-deep prefetch across tiles and level boundaries.
  //      Every LOAD reads rows whose stores precede it in program order. ----
  LOAD_B(bfA, 0, 31, 127);            // L7 t0 (reads L8 rows 0:32)
  LOAD_B(bfB, 32, 31, 159);           // L7 t1
  DO_TILE(bfA, BASE_PTR(0, 32), 1);   // L7 t0 -> rows 0:16
  LOAD_B(bfA, 64, 31, 191);           // L7 t2
  DO_TILE(bfB, BASE_PTR(16, 32), 1);  // L7 t1 -> 16:32
  LOAD_B(bfB, 96, 31, 223);           // L7 t3
  DO_TILE(bfA, BASE_PTR(32, 32), 1);  // L7 t2 -> 32:48
  LOAD_B(bfA, 0, 31, 63);             // L6 t0 (reads L7 rows 0:32)
  DO_TILE(bfB, BASE_PTR(48, 32), 1);  // L7 t3 -> 48:64
  LOAD_B(bfB, 32, 31, 95);            // L6 t1 (reads L7 rows 32:64)
  DO_TILE(bfA, BASE_PTR(0, 32), 1);   // L6 t0 -> 0:16
  DO_TILE(bfB, BASE_PTR(16, 32), 1);  // L6 t1 -> 16:32
  LOAD_B(bfA, 0, 31, 31);             // L5 (reads L6 rows 0:32)
  DO_TILE(bfA, BASE_PTR(0, 32), 1);   // L5 -> 0:16

  // ---- levels 4..1 (16,8,4,2 nodes): inherently serial ----
  #pragma unroll 1
  for (int d = 4; d >= 1; --d) {
    const int nn = 1 << d;
    LOAD_B(bfA, 0, nn - 1, nn - 1);
    _Float16* bse = BASE_PTR(0, nn);
    DO_TILE(bfA, bse, 1);
  }
  // ---- root: no sibling add; store h to row 0 ----
  {
    LOAD_B(bfA, 0, 0, 0);
    _Float16* bse = (c == 0) ? &Cs[0][0] : &trash[lane * 4];
    DO_TILE(bfA, bse, 0);
  }

  // ---- projection: out[p] = root . Pw[p] + Pb[p], p<5 (wave-wide) ----
  #pragma unroll 1
  for (int p = 0; p < 5; ++p) {
    float v = (float)Cs[0][lane] * Pw[p * 100 + lane];
    if (lane < 36) v += (float)Cs[0][64 + lane] * Pw[p * 100 + 64 + lane];
    v += __shfl_xor(v, 32, 64);
    v += __shfl_xor(v, 16, 64);
    v += __shfl_xor(v, 8, 64);
    v += __shfl_xor(v, 4, 64);
    v += __shfl_xor(v, 2, 64);
    v += __shfl_xor(v, 1, 64);
    if (lane == 0) out[tree * 5 + p] = v + Pb[p];
  }
#undef DO_TILE
#undef LOAD_B
#undef LEAF_BUILD
#undef BASE_PTR
}

extern "C" void kernel_launch(void* const* d_in, const int* in_sizes, int n_in,
                              void* d_out, int out_size, void* d_ws, size_t ws_size,
                              hipStream_t stream) {
  (void)n_in; (void)out_size; (void)d_ws; (void)ws_size;
  const float* times = (const float*)d_in[0];
  const float* Qw = (const float*)d_in[1];
  const float* Qb = (const float*)d_in[2];
  const float* Ww = (const float*)d_in[3];
  const float* Wb = (const float*)d_in[4];
  const float* Pw = (const float*)d_in[5];
  const float* Pb = (const float*)d_in[6];
  float* outp = (float*)d_out;
  const int B = in_sizes[0] / 1023;   // 1024 trees -> 1024 one-wave blocks
  grnn_fused<<<dim3(B), dim3(64), 0, stream>>>(times, Qw, Qb, Ww, Wb, Pw, Pb, outp);
}